// Round 4
// baseline (1120.464 us; speedup 1.0000x reference)
//
#include <hip/hip_runtime.h>
#include <math.h>

#define OBS 256
#define ACTD 64
#define NB 8192
#define NT 22
#define NSTEP 15

// ---------------------------------------------------------------------------
// Kernel 1: gi[g][j] = bias[j] + sum_k x[g][k] * Wih[j][k],  g=(b,t) row.
// Block=256 (4 waves) handles 64 rows. x staged in LDS as XL[k][r] (stride 65,
// conflict-free lane=row reads, coalesced float4 global loads, single fetch).
// Wave w computes j in [24w, 24w+24): 24 accumulators/thread (fits 64 VGPR),
// weights wave-uniform -> SGPR loads. K split in two 160-col halves so LDS
// stays under 64 KB.
// ---------------------------------------------------------------------------
__global__ __launch_bounds__(256) void k1_gi(
    const float* __restrict__ obs, const float* __restrict__ act,
    const float* __restrict__ Wih, const float* __restrict__ bih,
    float* __restrict__ gi)
{
    __shared__ float XL[160 * 65];            // 41.6 KB
    int w = threadIdx.x >> 6;                 // wave 0..3
    int r = threadIdx.x & 63;                 // lane = local row
    int g0 = blockIdx.x * 64;

    float acc[24];
    const float* bg = bih + w * 24;
#pragma unroll
    for (int j = 0; j < 24; ++j) acc[j] = bg[j];

#pragma unroll 1
    for (int half = 0; half < 2; ++half) {
        __syncthreads();                      // XL safe to overwrite
        // stage 64 rows x 160 cols (2560 float4, 10 per thread)
#pragma unroll
        for (int i = 0; i < 10; ++i) {
            int q  = threadIdx.x + i * 256;
            int rr = q / 40;
            int c4 = q - rr * 40;
            int g  = g0 + rr;
            int b  = g / 15;
            int t  = g - b * 15;
            const float* src;
            int kk;
            if (half == 0) {
                src = obs + (size_t)(b * NT + t) * OBS + c4 * 4;
                kk  = c4 * 4;
            } else if (c4 < 24) {
                src = obs + (size_t)(b * NT + t) * OBS + 160 + c4 * 4;
                kk  = c4 * 4;
            } else {
                src = act + (size_t)(b * NT + t) * ACTD + (c4 - 24) * 4;
                kk  = 96 + (c4 - 24) * 4;
            }
            float4 v = *(const float4*)src;
            XL[(kk + 0) * 65 + rr] = v.x;
            XL[(kk + 1) * 65 + rr] = v.y;
            XL[(kk + 2) * 65 + rr] = v.z;
            XL[(kk + 3) * 65 + rr] = v.w;
        }
        __syncthreads();

        const float* Wb = Wih + (size_t)(w * 24) * 320 + half * 160;
#pragma unroll 1
        for (int kk = 0; kk < 160; kk += 4) {
            float x0 = XL[(kk + 0) * 65 + r];
            float x1 = XL[(kk + 1) * 65 + r];
            float x2 = XL[(kk + 2) * 65 + r];
            float x3 = XL[(kk + 3) * 65 + r];
#pragma unroll
            for (int j = 0; j < 24; ++j) {
                const float* wp = Wb + j * 320 + kk;
                acc[j] = fmaf(wp[0], x0, acc[j]);
                acc[j] = fmaf(wp[1], x1, acc[j]);
                acc[j] = fmaf(wp[2], x2, acc[j]);
                acc[j] = fmaf(wp[3], x3, acc[j]);
            }
        }
    }

    float4* o = (float4*)(gi + (size_t)(g0 + r) * 96 + w * 24);
#pragma unroll
    for (int j = 0; j < 6; ++j)
        o[j] = make_float4(acc[4*j], acc[4*j+1], acc[4*j+2], acc[4*j+3]);
}

// ---------------------------------------------------------------------------
// Kernel 2a: GRU recurrence, lane <-> batch row (64 rows per wave, 1 wave per
// block). Weights wave-uniform (jj loop counter) -> SGPR loads, no VGPR cost.
// h[32] in registers; h' bounced through LDS (stride-33, conflict-free) so no
// second 32-reg array. ~50 VGPR total -> no spill at any occupancy target.
// ---------------------------------------------------------------------------
__global__ __launch_bounds__(64) void k2a_gru(
    const float* __restrict__ Whh, const float* __restrict__ bhh,
    const float* __restrict__ gi, float* __restrict__ hn)
{
    __shared__ float HNs[64 * 33];
    int r = threadIdx.x;                      // 0..63
    int row = blockIdx.x * 64 + r;            // batch index

    float h[32];
#pragma unroll
    for (int k = 0; k < 32; ++k) h[k] = 0.0f;

    const float2* G = (const float2*)(gi + (size_t)row * NSTEP * 96);

#pragma unroll 1
    for (int t = 0; t < NSTEP; ++t) {
        const float2* Gt = G + t * 48;        // 96 floats = 48 float2
#pragma unroll 1
        for (int c = 0; c < 16; ++c) {
            float2 g_r = Gt[c];
            float2 g_z = Gt[16 + c];
            float2 g_n = Gt[32 + c];
#pragma unroll
            for (int s = 0; s < 2; ++s) {
                int jj = 2 * c + s;           // wave-uniform
                float ar = bhh[jj], az = bhh[32 + jj], an = bhh[64 + jj];
#pragma unroll
                for (int k = 0; k < 32; ++k) {
                    float hk = h[k];
                    ar = fmaf(Whh[jj * 32 + k],        hk, ar);
                    az = fmaf(Whh[(32 + jj) * 32 + k], hk, az);
                    an = fmaf(Whh[(64 + jj) * 32 + k], hk, an);
                }
                float gr = s ? g_r.y : g_r.x;
                float gz = s ? g_z.y : g_z.x;
                float gn = s ? g_n.y : g_n.x;
                float rr = 1.0f / (1.0f + expf(-(gr + ar)));
                float zz = 1.0f / (1.0f + expf(-(gz + az)));
                float nn = tanhf(gn + rr * an);
                HNs[r * 33 + jj] = (1.0f - zz) * nn + zz * h[jj];
            }
        }
#pragma unroll
        for (int k = 0; k < 32; ++k) h[k] = HNs[r * 33 + k];
    }

    float4* o = (float4*)(hn + (size_t)row * 32);
#pragma unroll
    for (int j = 0; j < 8; ++j)
        o[j] = make_float4(h[4*j], h[4*j+1], h[4*j+2], h[4*j+3]);
}

// ---------------------------------------------------------------------------
// Kernel 2b: features + layernorm + MLP + argmax. One wave per batch row.
// h_n read from scratch; held as ONE register per lane (lane&31 -> component),
// broadcast via shfl. ~45 VGPR.
// ---------------------------------------------------------------------------
__global__ __launch_bounds__(64) void k2b_head(
    const float* __restrict__ obs, const float* __restrict__ act,
    const float* __restrict__ lng, const float* __restrict__ lnb,
    const float* __restrict__ W1, const float* __restrict__ b1,
    const float* __restrict__ W2, const float* __restrict__ b2,
    const float* __restrict__ W3, const float* __restrict__ b3,
    const float* __restrict__ hn,
    float* __restrict__ out_wl, float* __restrict__ out_mask)
{
    int b = blockIdx.x;
    int l = threadIdx.x;        // 0..63
    int jj = l & 31;

    float h_own = hn[(size_t)b * 32 + jj];   // lanes 32..63 duplicate 0..31

    // ---- features ----
    float o14v[4], o13v[4], o12v[4], o11v[4];
#pragma unroll
    for (int q = 0; q < 4; ++q) {
        int i = l + 64 * q;
        o14v[q] = obs[(size_t)(b * NT + 14) * OBS + i];
        o13v[q] = obs[(size_t)(b * NT + 13) * OBS + i];
        o12v[q] = obs[(size_t)(b * NT + 12) * OBS + i];
        o11v[q] = obs[(size_t)(b * NT + 11) * OBS + i];
    }
    float ap = act[(size_t)(b * NT + 13) * ACTD + l];   // act_prev

    // softmax entropy over obs_t (row 14)
    float m = fmaxf(fmaxf(o14v[0], o14v[1]), fmaxf(o14v[2], o14v[3]));
#pragma unroll
    for (int o = 32; o >= 1; o >>= 1) m = fmaxf(m, __shfl_xor(m, o, 64));
    float e[4];
    float S = 0.0f, so = 0.0f;
#pragma unroll
    for (int q = 0; q < 4; ++q) {
        e[q] = expf(o14v[q] - m);
        S += e[q];
        so += o14v[q];
    }
#pragma unroll
    for (int o = 32; o >= 1; o >>= 1) { S += __shfl_xor(S, o, 64); so += __shfl_xor(so, o, 64); }
    float ent = 0.0f;
#pragma unroll
    for (int q = 0; q < 4; ++q) {
        float p = e[q] / S;
        ent += p * logf(p + 1e-8f);
    }
#pragma unroll
    for (int o = 32; o >= 1; o >>= 1) ent += __shfl_xor(ent, o, 64);
    ent = -ent;

    // rate of change
    float d1 = 0.0f, d2 = 0.0f, d3 = 0.0f;
#pragma unroll
    for (int q = 0; q < 4; ++q) {
        float a = o12v[q] - o11v[q]; d1 = fmaf(a, a, d1);
        a = o13v[q] - o12v[q];       d2 = fmaf(a, a, d2);
        a = o14v[q] - o13v[q];       d3 = fmaf(a, a, d3);
    }
#pragma unroll
    for (int o = 32; o >= 1; o >>= 1) {
        d1 += __shfl_xor(d1, o, 64); d2 += __shfl_xor(d2, o, 64); d3 += __shfl_xor(d3, o, 64);
    }
    float roc = (sqrtf(d1) + sqrtf(d2) + sqrtf(d3)) / 3.0f;

    // correlation
    float sa = ap;
#pragma unroll
    for (int o = 32; o >= 1; o >>= 1) sa += __shfl_xor(sa, o, 64);
    float mu_o = so / 256.0f;
    float mu_a = sa / 256.0f;
    float s_oa = 0.0f, s_oo = 0.0f, s_aa = 0.0f;
#pragma unroll
    for (int q = 0; q < 4; ++q) {
        float ov = o14v[q] - mu_o;
        float av = ((q == 0) ? ap : 0.0f) - mu_a;
        s_oa = fmaf(ov, av, s_oa);
        s_oo = fmaf(ov, ov, s_oo);
        s_aa = fmaf(av, av, s_aa);
    }
#pragma unroll
    for (int o = 32; o >= 1; o >>= 1) {
        s_oa += __shfl_xor(s_oa, o, 64); s_oo += __shfl_xor(s_oo, o, 64); s_aa += __shfl_xor(s_aa, o, 64);
    }
    float corr = s_oa / (sqrtf(s_oo) * sqrtf(s_aa) + 1e-8f);

    // ---- layernorm stats over feats[35] = [ent, roc, corr, h(32)] ----
    float hs = h_own;
#pragma unroll
    for (int o = 16; o >= 1; o >>= 1) hs += __shfl_xor(hs, o, 64);  // sum of 32 h
    float mu = (ent + roc + corr + hs) / 35.0f;
    float hd = (h_own - mu);
    float hv = hd * hd;
#pragma unroll
    for (int o = 16; o >= 1; o >>= 1) hv += __shfl_xor(hv, o, 64);
    float vs = (ent - mu) * (ent - mu) + (roc - mu) * (roc - mu)
             + (corr - mu) * (corr - mu) + hv;
    float inv_sv = 1.0f / sqrtf(vs / 35.0f + 1e-5f);

    // ---- MLP: layernorm fused into W1 dot ----
    float x1 = b1[l];
#pragma unroll
    for (int k = 0; k < 3; ++k) {
        float f = (k == 0) ? ent : (k == 1) ? roc : corr;
        float fnk = (f - mu) * inv_sv * lng[k] + lnb[k];
        x1 = fmaf(W1[l * 35 + k], fnk, x1);
    }
#pragma unroll
    for (int k = 0; k < 32; ++k) {
        float hk = __shfl(h_own, k, 64);
        float fnk = (hk - mu) * inv_sv * lng[3 + k] + lnb[3 + k];
        x1 = fmaf(W1[l * 35 + 3 + k], fnk, x1);
    }
    x1 = fmaxf(x1, 0.0f);

    float x2 = b2[jj];
#pragma unroll
    for (int k = 0; k < 64; ++k)
        x2 = fmaf(W2[jj * 64 + k], __shfl(x1, k, 64), x2);
    x2 = fmaxf(x2, 0.0f);

    int lr = (l < 14) ? l : 0;
    float lg = b3[lr];
#pragma unroll
    for (int k = 0; k < 32; ++k)
        lg = fmaf(W3[lr * 32 + k], __shfl(x2, k, 64), lg);

    // argmax over 14 logits (first max wins), redundantly on all lanes
    float best = -3.402823466e38f;
    int bi = 0;
#pragma unroll
    for (int j = 0; j < 14; ++j) {
        float v = __shfl(lg, j, 64);
        if (v > best) { best = v; bi = j; }
    }
    int wl = bi + 2;
    if (l == 0) out_wl[b] = (float)wl;
    int s  = (wl - 1) >> 1;
    int ee = wl >> 1;
    if (l < 15) {
        int off = l - 7;
        out_mask[b * 15 + l] = (off >= -s && off <= ee) ? 1.0f : 0.0f;
    }
}

// ---------------------------------------------------------------------------
// Kernel 3: padded_window = concat(obs[:,7:22], act[:,7:22]) * mask
// ---------------------------------------------------------------------------
__global__ __launch_bounds__(256) void k3_window(
    const float* __restrict__ obs, const float* __restrict__ act,
    const float* __restrict__ mask, float* __restrict__ out_pad)
{
    int idx = blockIdx.x * 256 + threadIdx.x;     // < 9830400
    int bt = idx / 80;
    int k4 = idx - bt * 80;
    int b = bt / 15;
    int t = bt - b * 15;
    float mval = mask[bt];
    float4 v;
    if (k4 < 64) {
        v = *(const float4*)(obs + (size_t)(b * NT + 7 + t) * OBS + k4 * 4);
    } else {
        v = *(const float4*)(act + (size_t)(b * NT + 7 + t) * ACTD + (k4 - 64) * 4);
    }
    v.x *= mval; v.y *= mval; v.z *= mval; v.w *= mval;
    ((float4*)out_pad)[idx] = v;
}

extern "C" void kernel_launch(void* const* d_in, const int* in_sizes, int n_in,
                              void* d_out, int out_size, void* d_ws, size_t ws_size,
                              hipStream_t stream) {
    const float* obs = (const float*)d_in[0];
    const float* act = (const float*)d_in[1];
    const float* Wih = (const float*)d_in[2];
    const float* Whh = (const float*)d_in[3];
    const float* bih = (const float*)d_in[4];
    const float* bhh = (const float*)d_in[5];
    const float* lng = (const float*)d_in[6];
    const float* lnb = (const float*)d_in[7];
    const float* W1  = (const float*)d_in[8];
    const float* b1  = (const float*)d_in[9];
    const float* W2  = (const float*)d_in[10];
    const float* b2  = (const float*)d_in[11];
    const float* W3  = (const float*)d_in[12];
    const float* b3  = (const float*)d_in[13];

    float* out      = (float*)d_out;
    float* out_wl   = out;                      // 8192
    float* out_pad  = out + NB;                 // 39,321,600
    float* out_mask = out + NB + NB * 15 * 320; // 122,880

    // Scratch staged inside out_pad (consumed before k3 overwrites it):
    // gi: [0, 11.8M) floats;  hn: [16M, 16M+256K) floats.
    float* gi = out_pad;
    float* hn = out_pad + (16u << 20);

    k1_gi<<<1920, 256, 0, stream>>>(obs, act, Wih, bih, gi);
    k2a_gru<<<128, 64, 0, stream>>>(Whh, bhh, gi, hn);
    k2b_head<<<NB, 64, 0, stream>>>(obs, act, lng, lnb,
                                    W1, b1, W2, b2, W3, b3,
                                    hn, out_wl, out_mask);
    k3_window<<<38400, 256, 0, stream>>>(obs, act, out_mask, out_pad);
}